// Round 6
// baseline (1264.638 us; speedup 1.0000x reference)
//
#include <hip/hip_runtime.h>
#include <hip/hip_bf16.h>
#include <math.h>

#define NDIM 300
#define KPAD 320          // K padded: 300 x-dims + 3 normal dims + zeros
#define NREAL 1800
#define NPAD 1920         // 15 tiles of 128

typedef __hip_bfloat16 bf16;
typedef __attribute__((ext_vector_type(8))) short short8;   // 8 bf16 (4 VGPRs)
typedef __attribute__((ext_vector_type(4))) float f32x4;

__device__ __forceinline__ void gl_lds16(const void* g, void* l) {
    __builtin_amdgcn_global_load_lds(
        (const __attribute__((address_space(1))) void*)g,
        (__attribute__((address_space(3))) void*)l, 16, 0, 0);
}

__device__ __forceinline__ float wredsum(float v) {
    #pragma unroll
    for (int m = 1; m < 64; m <<= 1) v += __shfl_xor(v, m, 64);
    return v;
}

// ---------------- tiny constant-folding kernels ----------------
__global__ void small_pre(
    const float* __restrict__ Wn, const float* __restrict__ bn,
    const float* __restrict__ Wxy, const float* __restrict__ bxy,
    const float* __restrict__ Wloc, const float* __restrict__ bloc,
    const float* __restrict__ bobj,
    const float* __restrict__ Wfus,
    const float* __restrict__ vocab,
    float* __restrict__ Wn1, float* __restrict__ Wn2,
    float* __restrict__ Mxy, float* __restrict__ bgeo,
    float* __restrict__ vf5, float* __restrict__ t0, float* __restrict__ t1)
{
    int i = blockIdx.x * blockDim.x + threadIdx.x;
    if (i < 900) {
        int r = i / 300, c = i % 300;
        float s = 0.f;
        for (int k = 0; k < 300; k++) s += Wn[r*300+k] * Wloc[(300+k)*300+c];
        Wn1[i] = s;
    } else if (i < 1800) {
        int j = i - 900; int r = j/300, c = j%300;
        float s = 0.f;
        for (int k = 0; k < 300; k++) s += Wn[r*300+k] * Wloc[(600+k)*300+c];
        Wn2[j] = s;
    } else if (i < 2400) {
        int j = i - 1800; int r = j/300, c = j%300;
        float s = 0.f;
        for (int k = 0; k < 300; k++) s += Wxy[r*300+k] * Wloc[k*300+c];
        Mxy[j] = s;
    } else if (i < 2700) {
        int c = i - 2400;
        float s = bloc[c] + bobj[c];
        for (int k = 0; k < 300; k++) s += bxy[k] * Wloc[k*300+c];
        for (int k = 0; k < 300; k++) s += bn[k] * (Wloc[(300+k)*300+c] + Wloc[(600+k)*300+c]);
        bgeo[c] = s;
    } else if (i < 4200) {
        int j = i - 2700; int p = j/300, c = j%300;
        float s = 0.f;
        for (int k = 0; k < 300; k++) s += vocab[(2+p)*300+k] * Wfus[(300+k)*300+c];
        vf5[j] = s;
    } else if (i < 4500) {
        int c = i - 4200;
        float s = 0.f;
        for (int k = 0; k < 300; k++) s += vocab[k] * Wfus[k*300+c];
        t0[c] = s;
    } else if (i < 4800) {
        int c = i - 4500;
        float s = 0.f;
        for (int k = 0; k < 300; k++) s += vocab[300+k] * Wfus[k*300+c];
        t1[c] = s;
    }
}

__global__ void small_pre2(
    const float* __restrict__ We, const float* __restrict__ bfus,
    const float* __restrict__ vf5, const float* __restrict__ t0, const float* __restrict__ t1,
    const float* __restrict__ Wcls,
    float* __restrict__ E8, float* __restrict__ WclsT)
{
    int i = blockIdx.x * blockDim.x + threadIdx.x;
    if (i < 2400) {
        int r = i / 300, c = i % 300;
        const float* src;
        if (r == 0) src = t0;
        else if (r == 1) src = t1;
        else if (r == 7) src = bfus;
        else src = vf5 + (r - 2) * 300;
        float s = 0.f;
        for (int k = 0; k < 300; k++) s += src[k] * We[k*300+c];
        E8[i] = s;
    } else if (i < 3900) {
        int j = i - 2400; int cl = j / 300, c = j % 300;
        WclsT[cl * 300 + c] = Wcls[c * 5 + cl];
    }
}

// pack weights into WcatT[NPAD][KPAD] bf16 (transposed, K contiguous) + bcat fp32
__global__ void pack_w(
    const float* __restrict__ Wq, const float* __restrict__ Wk,
    const float* __restrict__ Wv, const float* __restrict__ Wskip,
    const float* __restrict__ Wobj,
    const float* __restrict__ Wn1, const float* __restrict__ Wn2,
    const float* __restrict__ bq, const float* __restrict__ bk,
    const float* __restrict__ bv, const float* __restrict__ bskip,
    bf16* __restrict__ WcatT, float* __restrict__ bcat)
{
    int i = blockIdx.x * blockDim.x + threadIdx.x;
    if (i < NREAL) {
        int seg = i / 300, jj = i % 300;
        float b = 0.f;
        if (seg == 0) b = bq[jj]; else if (seg == 1) b = bk[jj];
        else if (seg == 2) b = bv[jj]; else if (seg == 3) b = bskip[jj];
        bcat[i] = b;
    }
    if (i < NPAD * KPAD) {
        int c = i / KPAD, k = i % KPAD;
        float v = 0.f;
        if (c < NREAL) {
            int seg = c / 300, jj = c % 300;
            if (k < 300) {
                switch (seg) {
                    case 0: v = Wq[k*300+jj]; break;
                    case 1: v = Wk[k*300+jj]; break;
                    case 2: v = Wv[k*300+jj]; break;
                    case 3: v = Wskip[k*300+jj]; break;
                    case 4: v = Wobj[k*300+jj] - Wobj[(300+k)*300+jj]; break;
                    default: v = Wobj[(300+k)*300+jj]; break;
                }
            } else if (k < 303) {
                if (seg == 4) v = Wn1[(k-300)*300+jj];
                else if (seg == 5) v = Wn2[(k-300)*300+jj];
            }
        }
        WcatT[i] = __float2bfloat16(v);
    }
}

// ---------------- counting sort of edges by dst ----------------
__global__ void hist_k(const int* __restrict__ ei, int* __restrict__ deg, int E) {
    int e = blockIdx.x * blockDim.x + threadIdx.x;
    if (e < E) atomicAdd(&deg[ei[E + e]], 1);
}

__global__ __launch_bounds__(1024) void scan_k(
    const int* __restrict__ deg, int* __restrict__ off, int* __restrict__ cur, int N)
{
    __shared__ int buf[1024];
    __shared__ int carry;
    const int tid = threadIdx.x;
    if (tid == 0) carry = 0;
    __syncthreads();
    for (int base = 0; base < N; base += 1024) {
        int i = base + tid;
        int v = (i < N) ? deg[i] : 0;
        buf[tid] = v;
        __syncthreads();
        #pragma unroll
        for (int ofs = 1; ofs < 1024; ofs <<= 1) {
            int t = (tid >= ofs) ? buf[tid - ofs] : 0;
            __syncthreads();
            buf[tid] += t;
            __syncthreads();
        }
        int incl = buf[tid];
        int cbase = carry;
        if (i < N) { off[i] = cbase + incl - v; cur[i] = cbase + incl - v; }
        __syncthreads();
        if (tid == 0) carry = cbase + buf[1023];
        __syncthreads();
    }
    if (tid == 0) off[N] = carry;
}

// scatter: emit src id and edge_attr in dst-sorted order (kills per-edge indirection)
__global__ void scatter_k(const int* __restrict__ ei, const float* __restrict__ ea,
                          int* __restrict__ cur,
                          int* __restrict__ srcS, float* __restrict__ eaS, int E) {
    int e = blockIdx.x * blockDim.x + threadIdx.x;
    if (e < E) {
        int d = ei[E + e];
        int p = atomicAdd(&cur[d], 1);
        srcS[p] = ei[e];
        *(float4*)&eaS[(size_t)p * 4] = *(const float4*)&ea[(size_t)e * 4];
    }
}

// ---------------- MFMA node-GEMM: [N,320]bf16 @ [320,1920]bf16, double-buffered ----------------
// Epilogue writes packed layouts: QPi[n][600] = Q|Pi ; KVP[n][900] = K|V|Pj ; skip -> Ot fp32
__global__ __launch_bounds__(256) void gemm_mfma(
    const float* __restrict__ X, const float* __restrict__ Nrm,
    const bf16* __restrict__ Bt, const float* __restrict__ bcat,
    bf16* __restrict__ QPi, bf16* __restrict__ KVP,
    float* __restrict__ Ot, int M)
{
    __shared__ __align__(16) bf16 As[2][128 * 32];
    __shared__ __align__(16) bf16 Bs[2][128 * 32];

    const int tid  = threadIdx.x;
    const int wave = tid >> 6;
    const int lane = tid & 63;
    const int r0 = blockIdx.y * 128;
    const int c0 = blockIdx.x * 128;
    const int wm = (wave >> 1) * 64;
    const int wn = (wave & 1) * 64;
    const int lr = lane & 15;
    const int lq = lane >> 4;

    f32x4 acc[4][4];   // acc[j][i]: j = W-col subtile (MFMA M), i = X-row subtile (MFMA N)
    #pragma unroll
    for (int j = 0; j < 4; j++)
        #pragma unroll
        for (int i = 0; i < 4; i++) acc[j][i] = (f32x4){0.f, 0.f, 0.f, 0.f};

    const int arow_l = tid >> 1;
    const int akp    = (tid & 1) * 16;
    const int agrow  = min(r0 + arow_l, M - 1);
    const float* xr = X + (size_t)agrow * 300;
    const float* nr = Nrm + (size_t)agrow * 3;
    const int bcol_l = lane >> 2;
    const int bkp    = (lane & 3) * 8;

    auto stage = [&](int buf, int kb) {
        int g = kb + akp;
        union { bf16 h[16]; short8 s[2]; } u;
        if (g + 16 <= 300) {
            const float4 f0 = *(const float4*)(xr + g);
            const float4 f1 = *(const float4*)(xr + g + 4);
            const float4 f2 = *(const float4*)(xr + g + 8);
            const float4 f3 = *(const float4*)(xr + g + 12);
            u.h[0]=__float2bfloat16(f0.x); u.h[1]=__float2bfloat16(f0.y);
            u.h[2]=__float2bfloat16(f0.z); u.h[3]=__float2bfloat16(f0.w);
            u.h[4]=__float2bfloat16(f1.x); u.h[5]=__float2bfloat16(f1.y);
            u.h[6]=__float2bfloat16(f1.z); u.h[7]=__float2bfloat16(f1.w);
            u.h[8]=__float2bfloat16(f2.x); u.h[9]=__float2bfloat16(f2.y);
            u.h[10]=__float2bfloat16(f2.z); u.h[11]=__float2bfloat16(f2.w);
            u.h[12]=__float2bfloat16(f3.x); u.h[13]=__float2bfloat16(f3.y);
            u.h[14]=__float2bfloat16(f3.z); u.h[15]=__float2bfloat16(f3.w);
        } else {
            #pragma unroll
            for (int t = 0; t < 16; t++) {
                int gg = g + t;
                float v = 0.f;
                if (gg < 300)      v = xr[gg];
                else if (gg < 303) v = nr[gg - 300];
                u.h[t] = __float2bfloat16(v);
            }
        }
        *(short8*)&As[buf][arow_l * 32 + akp]     = u.s[0];
        *(short8*)&As[buf][arow_l * 32 + akp + 8] = u.s[1];
        #pragma unroll
        for (int h = 0; h < 2; h++) {
            int cloc = wave * 32 + h * 16;
            gl_lds16(Bt + (size_t)(c0 + cloc + bcol_l) * KPAD + kb + bkp,
                     &Bs[buf][cloc * 32]);
        }
    };

    stage(0, 0);
    #pragma unroll
    for (int it = 0; it < 10; it++) {
        __syncthreads();
        if (it < 9) stage((it + 1) & 1, (it + 1) * 32);
        const int b = it & 1;
        short8 af[4], bfr[4];
        #pragma unroll
        for (int i = 0; i < 4; i++)
            af[i] = *(const short8*)&As[b][(wm + i * 16 + lr) * 32 + lq * 8];
        #pragma unroll
        for (int j = 0; j < 4; j++)
            bfr[j] = *(const short8*)&Bs[b][(wn + j * 16 + lr) * 32 + lq * 8];
        #pragma unroll
        for (int j = 0; j < 4; j++)
            #pragma unroll
            for (int i = 0; i < 4; i++)
                acc[j][i] = __builtin_amdgcn_mfma_f32_16x16x32_bf16(
                    bfr[j], af[i], acc[j][i], 0, 0, 0);
    }

    // epilogue: X-row = lane&15, W-col = (lane>>4)*4 + reg ; 4 regs = 4 consecutive cols
    #pragma unroll
    for (int j = 0; j < 4; j++) {
        int colb = c0 + wn + j * 16 + lq * 4;
        if (colb >= NREAL) continue;
        int seg = colb / 300, jj = colb - seg * 300;
        float4 bb = *(const float4*)&bcat[colb];
        #pragma unroll
        for (int i = 0; i < 4; i++) {
            int row = r0 + wm + i * 16 + lr;
            if (row >= M) continue;
            float v0 = acc[j][i][0] + bb.x;
            float v1 = acc[j][i][1] + bb.y;
            float v2 = acc[j][i][2] + bb.z;
            float v3 = acc[j][i][3] + bb.w;
            if (seg == 3) {
                *(float4*)&Ot[(size_t)row * 300 + jj] = make_float4(v0, v1, v2, v3);
            } else {
                union { bf16 h[4]; uint2 u2; } p;
                p.h[0] = __float2bfloat16(v0); p.h[1] = __float2bfloat16(v1);
                p.h[2] = __float2bfloat16(v2); p.h[3] = __float2bfloat16(v3);
                size_t idx;
                if (seg == 0)      idx = (size_t)row * 600 + jj;          // Q
                else if (seg == 4) idx = (size_t)row * 600 + 300 + jj;    // Pi
                else if (seg == 1) idx = (size_t)row * 900 + jj;          // K
                else if (seg == 2) idx = (size_t)row * 900 + 300 + jj;    // V
                else               idx = (size_t)row * 900 + 600 + jj;    // Pj
                bf16* base = (seg == 0 || seg == 4) ? QPi : KVP;
                *(uint2*)&base[idx] = p.u2;
            }
        }
    }
}

// ---------------- QE8 precompute: QE8[n][h][t] = dot(Q[n] head h, E8[t] head h) ----------------
__global__ __launch_bounds__(256) void qe8_pre(
    const bf16* __restrict__ QPi, const float* __restrict__ E8,
    float* __restrict__ QE8, int N)
{
    const int wid  = threadIdx.x >> 6;
    const int lane = threadIdx.x & 63;
    const int n = blockIdx.x * 4 + wid;
    if (n >= N) return;
    const size_t qrow = (size_t)n * 600;
    #pragma unroll
    for (int h = 0; h < 4; h++) {
        float a[8];
        #pragma unroll
        for (int t = 0; t < 8; t++) a[t] = 0.f;
        #pragma unroll
        for (int part = 0; part < 2; part++) {
            int off = part * 64 + lane;
            bool val = off < 75;
            int c = h * 75 + (val ? off : 0);
            float qv = val ? __bfloat162float(QPi[qrow + c]) : 0.f;
            #pragma unroll
            for (int t = 0; t < 8; t++) a[t] += qv * E8[t * 300 + c];
        }
        #pragma unroll
        for (int t = 0; t < 8; t++) a[t] = wredsum(a[t]);
        if (lane == 0) {
            #pragma unroll
            for (int t = 0; t < 8; t++) QE8[(size_t)n * 32 + h * 8 + t] = a[t];
        }
    }
}

// ---------------- fused edge pipeline: wave per dst node, prefetched, factorized ----------------
__global__ __launch_bounds__(256) void edge_fused(
    const int* __restrict__ srcS, const float* __restrict__ eaS,
    const bf16* __restrict__ QPi, const bf16* __restrict__ KVP,
    const float* __restrict__ Mxy, const float* __restrict__ bgeo,
    const float* __restrict__ E8, const float* __restrict__ WclsT,
    const float* __restrict__ bcls, const float* __restrict__ QE8,
    const int* __restrict__ off,
    float* __restrict__ Ot, int N)
{
    const int wid  = threadIdx.x >> 6;
    const int lane = threadIdx.x & 63;
    const int n = blockIdx.x * 4 + wid;
    if (n >= N) return;
    const int e0 = off[n], e1 = off[n + 1];
    if (e0 == e1) return;                       // out stays = skip
    const size_t nrow = (size_t)n * 300;

    // per-node loads (clamped lane index; r==4 invalid lanes -> zeros)
    float qv[5], piv[5], mx0[5], mx1[5], bg[5], macc[5], wcl[5][5];
    #pragma unroll
    for (int r = 0; r < 5; r++) {
        int c = lane + 64 * r;
        bool ok = c < 300;
        int cc = ok ? c : 0;
        float m = ok ? 1.f : 0.f;
        qv[r]  = m * __bfloat162float(QPi[(size_t)n * 600 + cc]);
        piv[r] = m * __bfloat162float(QPi[(size_t)n * 600 + 300 + cc]);
        mx0[r] = m * Mxy[cc];
        mx1[r] = m * Mxy[300 + cc];
        bg[r]  = m * bgeo[cc];
        #pragma unroll
        for (int cl = 0; cl < 5; cl++) wcl[cl][r] = m * WclsT[cl * 300 + cc];
        macc[r] = 0.f;
    }
    float bc[5];
    #pragma unroll
    for (int cl = 0; cl < 5; cl++) bc[cl] = bcls[cl];
    f32x4 qe8v[8];                               // QE8[n][h][t] -> qe8v[h*2 + t/4][t%4]
    #pragma unroll
    for (int i = 0; i < 8; i++) qe8v[i] = *(const f32x4*)&QE8[(size_t)n * 32 + i * 4];
    float S[32];
    #pragma unroll
    for (int i = 0; i < 32; i++) S[i] = 0.f;

    float den0 = 0.f, den1 = 0.f, den2 = 0.f, den3 = 0.f;
    const float isc = 0.11547005383792516f;     // 1/sqrt(75)

    // ---- prefetch edge e0 ----
    int   sC = srcS[e0];
    float4 eaC = *(const float4*)&eaS[(size_t)e0 * 4];
    float pjP[5], kvP[5], vvP[5];
    {
        const bf16* row = KVP + (size_t)sC * 900;
        #pragma unroll
        for (int r = 0; r < 5; r++) {
            int c = lane + 64 * r;
            kvP[r] = __bfloat162float(row[c]);
            vvP[r] = __bfloat162float(row[300 + c]);
            pjP[r] = __bfloat162float(row[600 + c]);
        }
    }
    int   sN  = (e0 + 1 < e1) ? srcS[e0 + 1] : 0;
    float4 eaN = (e0 + 1 < e1) ? *(const float4*)&eaS[(size_t)(e0 + 1) * 4] : eaC;

    for (int t = e0; t < e1; t++) {
        // consume prefetched values (mask r==4 tail lanes)
        float pj[5], kv[5], vv[5];
        #pragma unroll
        for (int r = 0; r < 5; r++) {
            float m = (lane + 64 * r < 300) ? 1.f : 0.f;
            pj[r] = m * pjP[r]; kv[r] = m * kvP[r]; vv[r] = m * vvP[r];
        }
        const float ea0 = eaC.x, ea1 = eaC.y, ea2 = eaC.z, ea3 = eaC.w;
        // issue next edge's gathers (overlap with compute below)
        if (t + 1 < e1) {
            const bf16* row = KVP + (size_t)sN * 900;
            #pragma unroll
            for (int r = 0; r < 5; r++) {
                int c = lane + 64 * r;
                kvP[r] = __bfloat162float(row[c]);
                vvP[r] = __bfloat162float(row[300 + c]);
                pjP[r] = __bfloat162float(row[600 + c]);
            }
            eaC = eaN;
            if (t + 2 < e1) {
                sN  = srcS[t + 2];
                eaN = *(const float4*)&eaS[(size_t)(t + 2) * 4];
            }
        }

        // q.k partials (bucketed by head) -- independent of tanh path, overlaps
        float h0 = 0.f, h1 = 0.f, h2 = 0.f, h3 = 0.f;
        #pragma unroll
        for (int r = 0; r < 5; r++) {
            int c = lane + 64 * r;
            float p = qv[r] * kv[r];
            if (r == 0) h0 += p;
            else if (r == 1) { if (c < 75)  h0 += p; else h1 += p; }
            else if (r == 2) { if (c < 150) h1 += p; else h2 += p; }
            else if (r == 3) { if (c < 225) h2 += p; else h3 += p; }
            else h3 += p;
        }
        // tanh -> logits -> softmax
        float tt[5];
        #pragma unroll
        for (int r = 0; r < 5; r++) {
            float v = piv[r] + pj[r] + ea2 * mx0[r] + ea3 * mx1[r] + bg[r];
            v = fminf(fmaxf(v, -15.f), 15.f);
            float ex = __expf(2.f * v);
            tt[r] = (ex - 1.f) / (ex + 1.f);
        }
        float lg[5];
        #pragma unroll
        for (int cl = 0; cl < 5; cl++) {
            float p = 0.f;
            #pragma unroll
            for (int r = 0; r < 5; r++) p += tt[r] * wcl[cl][r];
            lg[cl] = p;
        }
        h0 = wredsum(h0); h1 = wredsum(h1); h2 = wredsum(h2); h3 = wredsum(h3);
        #pragma unroll
        for (int cl = 0; cl < 5; cl++) lg[cl] = wredsum(lg[cl]) + bc[cl];
        float mxv = lg[0];
        #pragma unroll
        for (int cl = 1; cl < 5; cl++) mxv = fmaxf(mxv, lg[cl]);
        float pr[5], psum = 0.f;
        #pragma unroll
        for (int cl = 0; cl < 5; cl++) { pr[cl] = __expf(lg[cl] - mxv); psum += pr[cl]; }
        const float pinv = 1.f / psum;
        #pragma unroll
        for (int cl = 0; cl < 5; cl++) pr[cl] *= pinv;
        const float cf0 = ea0 > 0.f ? 1.f : 0.f;
        const float cf1 = ea1 < 0.f ? 1.f : 0.f;
        float cf[8] = {cf0, cf1, pr[0], pr[1], pr[2], pr[3], pr[4], 1.f};

        // alpha_h = q.k + sum_t cf_t * qe8[h][t]
        float ax[4];
        #pragma unroll
        for (int h = 0; h < 4; h++) {
            float qk = (h == 0) ? h0 : (h == 1) ? h1 : (h == 2) ? h2 : h3;
            float qe = 0.f;
            #pragma unroll
            for (int tt8 = 0; tt8 < 8; tt8++)
                qe += cf[tt8] * qe8v[h * 2 + (tt8 >> 2)][tt8 & 3];
            ax[h] = __expf((qk + qe) * isc);
        }
        den0 += ax[0]; den1 += ax[1]; den2 += ax[2]; den3 += ax[3];
        // S[h][t] += ax_h * cf_t   (ef message contribution, applied after loop)
        #pragma unroll
        for (int h = 0; h < 4; h++)
            #pragma unroll
            for (int tt8 = 0; tt8 < 8; tt8++)
                S[h * 8 + tt8] += ax[h] * cf[tt8];
        // macc += ax_h * v
        #pragma unroll
        for (int r = 0; r < 5; r++) {
            int c = lane + 64 * r;
            float w = (r == 0) ? ax[0]
                    : (r == 1) ? (c < 75  ? ax[0] : ax[1])
                    : (r == 2) ? (c < 150 ? ax[1] : ax[2])
                    : (r == 3) ? (c < 225 ? ax[2] : ax[3])
                    : ax[3];
            macc[r] += w * vv[r];
        }
    }

    // apply factored ef contribution: macc[c] += sum_t S[h(c)][t] * E8[t][c]
    #pragma unroll
    for (int r = 0; r < 5; r++) {
        int c = lane + 64 * r;
        bool ok = c < 300;
        int cc = ok ? c : 0;
        float a = 0.f;
        if (r == 0) {
            #pragma unroll
            for (int t8 = 0; t8 < 8; t8++) a += S[t8] * E8[t8 * 300 + cc];
        } else if (r == 4) {
            #pragma unroll
            for (int t8 = 0; t8 < 8; t8++) a += S[24 + t8] * E8[t8 * 300 + cc];
        } else {
            int hi = r, lo = r - 1;           // head = (c < 75*r) ? r-1 : r
            bool low = c < 75 * r;
            #pragma unroll
            for (int t8 = 0; t8 < 8; t8++) {
                float sv = low ? S[lo * 8 + t8] : S[hi * 8 + t8];
                a += sv * E8[t8 * 300 + cc];
            }
        }
        macc[r] += ok ? a : 0.f;
    }

    const float rd0 = 1.f / den0, rd1 = 1.f / den1, rd2 = 1.f / den2, rd3 = 1.f / den3;
    #pragma unroll
    for (int r = 0; r < 5; r++) {
        int c = lane + 64 * r;
        if (c < 300) {
            float rd = (r == 0) ? rd0
                     : (r == 1) ? (c < 75  ? rd0 : rd1)
                     : (r == 2) ? (c < 150 ? rd1 : rd2)
                     : (r == 3) ? (c < 225 ? rd2 : rd3)
                     : rd3;
            Ot[nrow + c] += macc[r] * rd;
        }
    }
}

// ---------------- launch ----------------
extern "C" void kernel_launch(void* const* d_in, const int* in_sizes, int n_in,
                              void* d_out, int out_size, void* d_ws, size_t ws_size,
                              hipStream_t stream)
{
    const float* x     = (const float*)d_in[0];
    const int*   ei    = (const int*)  d_in[1];
    const float* ea    = (const float*)d_in[2];
    const float* on    = (const float*)d_in[3];
    const float* Wq    = (const float*)d_in[4];
    const float* bq    = (const float*)d_in[5];
    const float* Wk    = (const float*)d_in[6];
    const float* bk    = (const float*)d_in[7];
    const float* Wv    = (const float*)d_in[8];
    const float* bv    = (const float*)d_in[9];
    const float* We    = (const float*)d_in[10];
    const float* Wn    = (const float*)d_in[11];
    const float* bn    = (const float*)d_in[12];
    const float* Wxy   = (const float*)d_in[13];
    const float* bxy   = (const float*)d_in[14];
    const float* Wloc  = (const float*)d_in[15];
    const float* bloc  = (const float*)d_in[16];
    const float* Wobj  = (const float*)d_in[17];
    const float* bobj  = (const float*)d_in[18];
    const float* Wfus  = (const float*)d_in[19];
    const float* bfus  = (const float*)d_in[20];
    const float* Wcls  = (const float*)d_in[21];
    const float* bcls  = (const float*)d_in[22];
    const float* Wskip = (const float*)d_in[23];
    const float* bskip = (const float*)d_in[24];
    const float* vocab = (const float*)d_in[25];

    const int N = in_sizes[0] / NDIM;
    const int E = in_sizes[1] / 2;

    // ---- workspace layout: bf16 region, fp32 region, int region ----
    const size_t qpiElems = (size_t)N * 600 + 64;
    const size_t kvpElems = (size_t)N * 900 + 64;
    const size_t wcatElems = (size_t)NPAD * KPAD;
    const size_t bf16Elems = qpiElems + kvpElems + wcatElems;
    const size_t f32Elems  = (size_t)E * 4 + (size_t)N * 32
                           + NREAL + 904 + 904 + 600 + 304 + 1504 + 304 + 304 + 2400 + 1504;
    const size_t intElems  = (size_t)N + (size_t)(N + 1) + (size_t)N + (size_t)E;
    size_t need = bf16Elems * sizeof(bf16) + f32Elems * sizeof(float) + intElems * sizeof(int);
    if (ws_size < need) return;   // clean failure signal instead of OOB fault

    bf16* wsh = (bf16*)d_ws;
    bf16* QPib  = wsh;
    bf16* KVPb  = QPib + qpiElems;
    bf16* WcatT = KVPb + kvpElems;
    float* ws = (float*)(WcatT + wcatElems);
    size_t o = 0;
    float* eaS   = ws + o; o += (size_t)E * 4;     // first: keeps 16B alignment
    float* QE8b  = ws + o; o += (size_t)N * 32;
    float* bcat  = ws + o; o += NREAL;
    float* Wn1   = ws + o; o += 904;
    float* Wn2   = ws + o; o += 904;
    float* Mxyb  = ws + o; o += 600;
    float* bgeo  = ws + o; o += 304;
    float* vf5   = ws + o; o += 1504;
    float* t0b   = ws + o; o += 304;
    float* t1b   = ws + o; o += 304;
    float* E8b   = ws + o; o += 2400;
    float* WclsT = ws + o; o += 1504;
    int* ip = (int*)(ws + o);
    int* deg    = ip;             ip += N;
    int* offb   = ip;             ip += N + 1;
    int* curb   = ip;             ip += N;
    int* srcS   = ip;             ip += E;
    (void)n_in; (void)out_size;

    hipMemsetAsync(deg, 0, (size_t)N * sizeof(int), stream);

    small_pre<<<19, 256, 0, stream>>>(Wn, bn, Wxy, bxy, Wloc, bloc, bobj, Wfus, vocab,
                                      Wn1, Wn2, Mxyb, bgeo, vf5, t0b, t1b);
    small_pre2<<<16, 256, 0, stream>>>(We, bfus, vf5, t0b, t1b, Wcls, E8b, WclsT);
    pack_w<<<(NPAD * KPAD + 255) / 256, 256, 0, stream>>>(
        Wq, Wk, Wv, Wskip, Wobj, Wn1, Wn2, bq, bk, bv, bskip, WcatT, bcat);

    const int ebk = (E + 255) / 256;
    hist_k<<<ebk, 256, 0, stream>>>(ei, deg, E);
    scan_k<<<1, 1024, 0, stream>>>(deg, offb, curb, N);
    scatter_k<<<ebk, 256, 0, stream>>>(ei, ea, curb, srcS, eaS, E);

    dim3 g1(NPAD / 128, (N + 127) / 128);
    gemm_mfma<<<g1, 256, 0, stream>>>(x, on, WcatT, bcat, QPib, KVPb, (float*)d_out, N);

    const int nb = (N + 3) / 4;
    qe8_pre<<<nb, 256, 0, stream>>>(QPib, E8b, QE8b, N);
    edge_fused<<<nb, 256, 0, stream>>>(srcS, eaS, QPib, KVPb,
                                       Mxyb, bgeo, E8b, WclsT, bcls, QE8b,
                                       offb, (float*)d_out, N);
}